// Round 4
// baseline (366.925 us; speedup 1.0000x reference)
//
#include <hip/hip_runtime.h>

// OU Euler-Maruyama: x_{i+1} = a*x_i + b_i,  a = 1 - gamma*dt (per-chain const),
// b_i = gamma*mu*dt + sigma*sqrt(dt)*eps_i.
//
// Block-level affine scan, ONE 256-thread block (4 waves) per chain, CHUNK=16:
//  - per lane: 16-step local affine compose (registers)
//  - per wave: 64-lane scan of the offset term only — the multiplier of every
//    lane's map is the SAME scalar a^16, so scan step d needs just
//    B += a^(16d) * shfl_up(B,d): 1 shfl + 1 fma (a-powers precomputed).
//  - per block: lane-63 wave offsets -> LDS (double-buffered), 1 barrier,
//    wave prefix/carry composed with uniform a^1024 weights.
//  - 5 block-tiles of 4096 steps; carry across tiles.
//  - nontemporal float4 stores (via clang ext_vector type — HIP float4 is a
//    class and the builtin rejects it): out is write-once; bypassing cache
//    keeps the 164 MB noise buffer resident in the 256 MB L3 (round-1
//    FETCH_SIZE=86 MB showed write traffic was evicting it).

#define T_STEPS 20000
#define M_PATHS 64
#define CHUNK   16                      // elements per lane per tile
#define NWAVES  4
#define BLOCK   (NWAVES * 64)           // 256
#define BTILE   (BLOCK * CHUNK)         // 4096 steps per block-tile
#define NBT     ((T_STEPS + BTILE - 1) / BTILE)  // 5 (last tile: 3616 elems)
#define DT      0.01f
#define SQRT_DT 0.1f

typedef float f32x4 __attribute__((ext_vector_type(4)));

__global__ __launch_bounds__(BLOCK, 8) void ou_scan_kernel(
    const float* __restrict__ theta,
    const float* __restrict__ noise,
    float* __restrict__ out)
{
    __shared__ float sB[2][NWAVES];

    const int tid   = threadIdx.x;
    const int wave  = tid >> 6;
    const int lane  = tid & 63;
    const int chain = blockIdx.x;            // 0 .. 2047
    const int n     = chain >> 6;            // chain / M_PATHS -> theta row

    const float gamma = theta[n * 4 + 0];
    const float mu    = theta[n * 4 + 1];
    const float sigma = theta[n * 4 + 2];
    float carry       = theta[n * 4 + 3];    // x_0 (uniform across block)

    const float a    = 1.0f - gamma * DT;
    const float gmdt = gamma * mu * DT;
    const float ssd  = sigma * SQRT_DT;

    // powers of a by repeated squaring (uniform per block -> scalar regs)
    const float a2    = a * a;
    const float a4    = a2 * a2;
    const float a8    = a4 * a4;
    const float a16   = a8 * a8;
    const float a32   = a16 * a16;
    const float a64   = a32 * a32;
    const float a128  = a64 * a64;
    const float a256  = a128 * a128;
    const float a512  = a256 * a256;
    const float a1024 = a512 * a512;
    const float a2048 = a1024 * a1024;
    const float a4096 = a2048 * a2048;       // full-block-tile multiplier

    // per-lane exclusive multiplier within wave: a^(16*lane)  (no cross-lane)
    float Aex = 1.f;
    if (lane & 1)  Aex *= a16;
    if (lane & 2)  Aex *= a32;
    if (lane & 4)  Aex *= a64;
    if (lane & 8)  Aex *= a128;
    if (lane & 16) Aex *= a256;
    if (lane & 32) Aex *= a512;

    // per-wave exclusive multiplier: a^(1024*wave)
    float PA = 1.f;
    if (wave & 1) PA *= a1024;
    if (wave & 2) PA *= a2048;
    const float FA = a4096;

    const float* __restrict__ np_ = noise + (size_t)chain * T_STEPS;
    float* __restrict__       op_ = out   + (size_t)chain * T_STEPS;

    // ---- prefetch tile 0 (full tile) ----
    float4 c0, c1, c2, c3;
    {
        const int e0 = tid * CHUNK;
        c0 = *(const float4*)(np_ + e0);
        c1 = *(const float4*)(np_ + e0 + 4);
        c2 = *(const float4*)(np_ + e0 + 8);
        c3 = *(const float4*)(np_ + e0 + 12);
    }

    for (int tb = 0; tb < NBT; ++tb) {
        // ---- prefetch next tile (in flight across this tile's compute) ----
        float4 n0 = make_float4(0.f,0.f,0.f,0.f), n1 = n0, n2 = n0, n3 = n0;
        const int ne0 = (tb + 1) * BTILE + tid * CHUNK;
        if (ne0 + CHUNK <= T_STEPS) {
            n0 = *(const float4*)(np_ + ne0);
            n1 = *(const float4*)(np_ + ne0 + 4);
            n2 = *(const float4*)(np_ + ne0 + 8);
            n3 = *(const float4*)(np_ + ne0 + 12);
        }

        const int  base = tb * BTILE + tid * CHUNK;
        const bool act  = (base + CHUNK <= T_STEPS);

        // local 16-step affine compose: x_out = a^16 * x_in + p
        // (b_j = gmdt + ssd*eps_j folded in; b's not kept live)
        float p;
        p = fmaf(ssd, c0.x, gmdt);
        p = fmaf(p, a, fmaf(ssd, c0.y, gmdt));
        p = fmaf(p, a, fmaf(ssd, c0.z, gmdt));
        p = fmaf(p, a, fmaf(ssd, c0.w, gmdt));
        p = fmaf(p, a, fmaf(ssd, c1.x, gmdt));
        p = fmaf(p, a, fmaf(ssd, c1.y, gmdt));
        p = fmaf(p, a, fmaf(ssd, c1.z, gmdt));
        p = fmaf(p, a, fmaf(ssd, c1.w, gmdt));
        p = fmaf(p, a, fmaf(ssd, c2.x, gmdt));
        p = fmaf(p, a, fmaf(ssd, c2.y, gmdt));
        p = fmaf(p, a, fmaf(ssd, c2.z, gmdt));
        p = fmaf(p, a, fmaf(ssd, c2.w, gmdt));
        p = fmaf(p, a, fmaf(ssd, c3.x, gmdt));
        p = fmaf(p, a, fmaf(ssd, c3.y, gmdt));
        p = fmaf(p, a, fmaf(ssd, c3.z, gmdt));
        p = fmaf(p, a, fmaf(ssd, c3.w, gmdt));

        float B = act ? p : 0.f;   // inactive tail lanes: zero offset

        // uniform-weight inclusive scan of offsets (1 shfl + 1 fma per step)
        {
            float t;
            t = __shfl_up(B, 1);  if (lane >= 1)  B = fmaf(a16,  t, B);
            t = __shfl_up(B, 2);  if (lane >= 2)  B = fmaf(a32,  t, B);
            t = __shfl_up(B, 4);  if (lane >= 4)  B = fmaf(a64,  t, B);
            t = __shfl_up(B, 8);  if (lane >= 8)  B = fmaf(a128, t, B);
            t = __shfl_up(B, 16); if (lane >= 16) B = fmaf(a256, t, B);
            t = __shfl_up(B, 32); if (lane >= 32) B = fmaf(a512, t, B);
        }

        // publish wave offset; double-buffered so ONE barrier per tile
        if (lane == 63) sB[tb & 1][wave] = B;
        __syncthreads();

        // wave-exclusive offset PB and full-block offset FB (uniform a^1024)
        float PB = 0.f, pb = 0.f;
        #pragma unroll
        for (int v = 0; v < NWAVES; ++v) {
            if (v == wave) PB = pb;
            pb = fmaf(pb, a1024, sB[tb & 1][v]);
        }
        const float FB = pb;

        const float xw = fmaf(PA, carry, PB);     // state entering this wave

        float Bex = __shfl_up(B, 1);
        if (lane == 0) Bex = 0.f;
        float x = fmaf(Aex, xw, Bex);             // state entering this lane

        carry = fmaf(FA, carry, FB);              // carry across block-tiles
        // (tail tile's FB is garbage from partial wave 3, but carry is unused
        //  after the final tile)

        if (act) {
            f32x4 o0, o1, o2, o3;
            x = fmaf(a, x, fmaf(ssd, c0.x, gmdt)); o0.x = x;
            x = fmaf(a, x, fmaf(ssd, c0.y, gmdt)); o0.y = x;
            x = fmaf(a, x, fmaf(ssd, c0.z, gmdt)); o0.z = x;
            x = fmaf(a, x, fmaf(ssd, c0.w, gmdt)); o0.w = x;
            x = fmaf(a, x, fmaf(ssd, c1.x, gmdt)); o1.x = x;
            x = fmaf(a, x, fmaf(ssd, c1.y, gmdt)); o1.y = x;
            x = fmaf(a, x, fmaf(ssd, c1.z, gmdt)); o1.z = x;
            x = fmaf(a, x, fmaf(ssd, c1.w, gmdt)); o1.w = x;
            x = fmaf(a, x, fmaf(ssd, c2.x, gmdt)); o2.x = x;
            x = fmaf(a, x, fmaf(ssd, c2.y, gmdt)); o2.y = x;
            x = fmaf(a, x, fmaf(ssd, c2.z, gmdt)); o2.z = x;
            x = fmaf(a, x, fmaf(ssd, c2.w, gmdt)); o2.w = x;
            x = fmaf(a, x, fmaf(ssd, c3.x, gmdt)); o3.x = x;
            x = fmaf(a, x, fmaf(ssd, c3.y, gmdt)); o3.y = x;
            x = fmaf(a, x, fmaf(ssd, c3.z, gmdt)); o3.z = x;
            x = fmaf(a, x, fmaf(ssd, c3.w, gmdt)); o3.w = x;
            // write-streaming: keep L3 for the noise buffer
            __builtin_nontemporal_store(o0, (f32x4*)(op_ + base));
            __builtin_nontemporal_store(o1, (f32x4*)(op_ + base + 4));
            __builtin_nontemporal_store(o2, (f32x4*)(op_ + base + 8));
            __builtin_nontemporal_store(o3, (f32x4*)(op_ + base + 12));
        }

        c0 = n0; c1 = n1; c2 = n2; c3 = n3;
    }
}

extern "C" void kernel_launch(void* const* d_in, const int* in_sizes, int n_in,
                              void* d_out, int out_size, void* d_ws, size_t ws_size,
                              hipStream_t stream) {
    const float* theta = (const float*)d_in[0];
    const float* noise = (const float*)d_in[1];
    float* out = (float*)d_out;

    const int chains = in_sizes[1] / T_STEPS;   // 2048
    ou_scan_kernel<<<chains, BLOCK, 0, stream>>>(theta, noise, out);
}

// Round 5
// 287.521 us; speedup vs baseline: 1.2762x; 1.2762x over previous
//
#include <hip/hip_runtime.h>

// OU Euler-Maruyama: x_{i+1} = a*x_i + b_i,  a = 1 - gamma*dt (per-chain const),
// b_i = gamma*mu*dt + sigma*sqrt(dt)*eps_i.
//
// Block-level affine scan, ONE 512-thread block (8 waves) per chain, CHUNK=4:
//  - COALESCED global access: lane l owns elements [4l,4l+4) of the tile, so
//    every wave load/store is 64 consecutive float4s = 1 KB contiguous.
//    (R1-R4 used CHUNK>=8 -> 128-256B lane stride -> 64 line-touches per
//    instruction -> ~0.78 req/cy/CU: L1 request-rate bound at ~2.5 TB/s.)
//  - per lane: 4-step local affine compose; per-lane multiplier is the SAME
//    scalar a^4, so the wave scan needs only B += a^(4d)*shfl_up(B,d).
//  - per block: lane-63 wave offsets -> LDS (double-buffered), 1 barrier/tile,
//    wave prefix/carry composed with uniform a^256 weights.
//  - 10 block-tiles of 2048 steps; carry across tiles (tail tile: 1568 elems,
//    = 392 fully-active lanes; inactive lanes publish zeros, never stored).
//  - nontemporal stores are SAFE now: stores are full-line (1 KB/wave), so the
//    R4 partial-line write amplification (276 MB vs 164 MB) cannot occur, and
//    bypassing L3 keeps the 164 MB noise buffer resident.

#define T_STEPS 20000
#define M_PATHS 64
#define CHUNK   4                       // elements per lane per tile (1 float4)
#define NWAVES  8
#define BLOCK   (NWAVES * 64)           // 512
#define BTILE   (BLOCK * CHUNK)         // 2048 steps per block-tile
#define NBT     ((T_STEPS + BTILE - 1) / BTILE)  // 10 (last tile: 1568 elems)
#define DT      0.01f
#define SQRT_DT 0.1f

typedef float f32x4 __attribute__((ext_vector_type(4)));

__global__ __launch_bounds__(BLOCK, 8) void ou_scan_kernel(
    const float* __restrict__ theta,
    const float* __restrict__ noise,
    float* __restrict__ out)
{
    __shared__ float sB[2][NWAVES];

    const int tid   = threadIdx.x;
    const int wave  = tid >> 6;
    const int lane  = tid & 63;
    const int chain = blockIdx.x;            // 0 .. 2047
    const int n     = chain >> 6;            // chain / M_PATHS -> theta row

    const float gamma = theta[n * 4 + 0];
    const float mu    = theta[n * 4 + 1];
    const float sigma = theta[n * 4 + 2];
    float carry       = theta[n * 4 + 3];    // x_0 (uniform across block)

    const float a    = 1.0f - gamma * DT;
    const float gmdt = gamma * mu * DT;
    const float ssd  = sigma * SQRT_DT;

    // powers of a by repeated squaring (uniform per block)
    const float a2    = a * a;
    const float a4    = a2 * a2;     // per-lane segment multiplier
    const float a8    = a4 * a4;
    const float a16   = a8 * a8;
    const float a32   = a16 * a16;
    const float a64   = a32 * a32;
    const float a128  = a64 * a64;
    const float a256  = a128 * a128; // per-wave segment multiplier
    const float a512  = a256 * a256;
    const float a1024 = a512 * a512;
    const float a2048 = a1024 * a1024; // full-block-tile multiplier

    // per-lane exclusive multiplier within wave: a^(4*lane)
    float Aex = 1.f;
    if (lane & 1)  Aex *= a4;
    if (lane & 2)  Aex *= a8;
    if (lane & 4)  Aex *= a16;
    if (lane & 8)  Aex *= a32;
    if (lane & 16) Aex *= a64;
    if (lane & 32) Aex *= a128;

    // per-wave exclusive multiplier: a^(256*wave)
    float PA = 1.f;
    if (wave & 1) PA *= a256;
    if (wave & 2) PA *= a512;
    if (wave & 4) PA *= a1024;
    const float FA = a2048;

    const float* __restrict__ np_ = noise + (size_t)chain * T_STEPS;
    float* __restrict__       op_ = out   + (size_t)chain * T_STEPS;

    // ---- prefetch tile 0 (full tile), coalesced: lane-consecutive float4 ----
    float4 c = *(const float4*)(np_ + tid * CHUNK);

    for (int tb = 0; tb < NBT; ++tb) {
        // ---- prefetch next tile (in flight across this tile's compute) ----
        float4 nx = make_float4(0.f, 0.f, 0.f, 0.f);
        const int ne0 = (tb + 1) * BTILE + tid * CHUNK;
        if (ne0 + CHUNK <= T_STEPS) nx = *(const float4*)(np_ + ne0);

        const int  base = tb * BTILE + tid * CHUNK;
        const bool act  = (base + CHUNK <= T_STEPS);

        // b_j = gmdt + ssd * eps_j
        const float b0 = fmaf(ssd, c.x, gmdt);
        const float b1 = fmaf(ssd, c.y, gmdt);
        const float b2 = fmaf(ssd, c.z, gmdt);
        const float b3 = fmaf(ssd, c.w, gmdt);

        // local 4-step affine compose: x_out = a^4 * x_in + p
        float p = b0;
        p = fmaf(p, a, b1);
        p = fmaf(p, a, b2);
        p = fmaf(p, a, b3);

        float B = act ? p : 0.f;   // inactive tail lanes: zero offset

        // uniform-weight inclusive scan of offsets (1 shfl + 1 fma per step)
        {
            float t;
            t = __shfl_up(B, 1);  if (lane >= 1)  B = fmaf(a4,   t, B);
            t = __shfl_up(B, 2);  if (lane >= 2)  B = fmaf(a8,   t, B);
            t = __shfl_up(B, 4);  if (lane >= 4)  B = fmaf(a16,  t, B);
            t = __shfl_up(B, 8);  if (lane >= 8)  B = fmaf(a32,  t, B);
            t = __shfl_up(B, 16); if (lane >= 16) B = fmaf(a64,  t, B);
            t = __shfl_up(B, 32); if (lane >= 32) B = fmaf(a128, t, B);
        }

        // publish wave offset; double-buffered so ONE barrier per tile
        if (lane == 63) sB[tb & 1][wave] = B;
        __syncthreads();

        // wave-exclusive offset PB and full-block offset FB (uniform a^256)
        float PB = 0.f, pb = 0.f;
        #pragma unroll
        for (int v = 0; v < NWAVES; ++v) {
            if (v == wave) PB = pb;
            pb = fmaf(pb, a256, sB[tb & 1][v]);
        }

        const float xw = fmaf(PA, carry, PB);     // state entering this wave

        float Bex = __shfl_up(B, 1);
        if (lane == 0) Bex = 0.f;
        float x = fmaf(Aex, xw, Bex);             // state entering this lane

        carry = fmaf(FA, carry, pb);              // pb == FB; carry across tiles
        // (tail tile's FB is garbage from partial waves, but carry is unused
        //  after the final tile)

        if (act) {
            f32x4 o;
            x = fmaf(a, x, b0); o.x = x;
            x = fmaf(a, x, b1); o.y = x;
            x = fmaf(a, x, b2); o.z = x;
            x = fmaf(a, x, b3); o.w = x;
            // full-line coalesced nontemporal store: no partial-line
            // amplification possible; keeps noise L3-resident
            __builtin_nontemporal_store(o, (f32x4*)(op_ + base));
        }

        c = nx;
    }
}

extern "C" void kernel_launch(void* const* d_in, const int* in_sizes, int n_in,
                              void* d_out, int out_size, void* d_ws, size_t ws_size,
                              hipStream_t stream) {
    const float* theta = (const float*)d_in[0];
    const float* noise = (const float*)d_in[1];
    float* out = (float*)d_out;

    const int chains = in_sizes[1] / T_STEPS;   // 2048
    ou_scan_kernel<<<chains, BLOCK, 0, stream>>>(theta, noise, out);
}

// Round 6
// 285.204 us; speedup vs baseline: 1.2865x; 1.0081x over previous
//
#include <hip/hip_runtime.h>

// OU Euler-Maruyama: x_{i+1} = a*x_i + b_i,  a = 1 - gamma*dt (per-chain const),
// b_i = gamma*mu*dt + sigma*sqrt(dt)*eps_i.
//
// Burst-load segment scan. ONE 512-thread block (8 waves) per chain; wave w
// owns the contiguous segment [2560w, 2560w+2560) (wave 7 ragged: 2080 real).
//
// R5 post-mortem: coalescing fixed WRITE amplification (exactly 160 MB) but
// time stayed ~100us at 2.5 TB/s, VALUBusy 14% -> latency-bound. The per-tile
// __syncthreads drains vmcnt(0) (barrier drain), killing the 1-deep prefetch
// every tile; in-flight bytes/CU ~23KB -> ~3 B/cy/CU by Little's law. This
// version issues ALL loads up front (10 independent float4/lane = 10 KB/wave,
// ~240 KB/CU in flight), keeps them in registers for the whole kernel (noise
// read ONCE), and has exactly ONE barrier (after all loads are consumed).
//
//  phase 1: per-lane weighted accumulation of the segment offset
//           S_w = sum_l a^(4(63-l)) * [fold_r acc = a^256 acc + p_{r,l}]
//           + one shfl_xor butterfly reduce; lane 0 -> LDS (8 floats).
//  barrier (single; vmcnt drain is free here).
//  prefix:  all waves walk the 8 LDS values: myStart = state at segment start.
//  phase 2: per round r: wave scan of offsets (uniform weight a^4d: 1 shfl +
//           1 fma per step), position via Aex=a^(4 lane), 4 outputs, NT store
//           (full-line coalesced -> no partial-line amplification; bypasses
//           caches so the single-read noise doesn't get evicted).

#define T_STEPS 20000
#define M_PATHS 64
#define NWAVES  8
#define BLOCK   (NWAVES * 64)           // 512
#define SEG     2560                    // nominal steps per wave; 8*2560=20480
#define ROUNDS  10                      // SEG / 256
#define DT      0.01f
#define SQRT_DT 0.1f

typedef float f32x4 __attribute__((ext_vector_type(4)));

__global__ __launch_bounds__(BLOCK, 4) void ou_scan_kernel(
    const float* __restrict__ theta,
    const float* __restrict__ noise,
    float* __restrict__ out)
{
    __shared__ float sS[NWAVES];

    const int tid   = threadIdx.x;
    const int wave  = tid >> 6;
    const int lane  = tid & 63;
    const int chain = blockIdx.x;            // 0 .. 2047
    const int n     = chain >> 6;            // theta row

    const float gamma = theta[n * 4 + 0];
    const float mu    = theta[n * 4 + 1];
    const float sigma = theta[n * 4 + 2];
    const float x0    = theta[n * 4 + 3];

    const float a    = 1.0f - gamma * DT;
    const float gmdt = gamma * mu * DT;
    const float ssd  = sigma * SQRT_DT;

    // powers of a (uniform per block)
    const float a2    = a * a;
    const float a4    = a2 * a2;
    const float a8    = a4 * a4;
    const float a16   = a8 * a8;
    const float a32   = a16 * a16;
    const float a64   = a32 * a32;
    const float a128  = a64 * a64;
    const float a256  = a128 * a128;   // per-round multiplier
    const float a512  = a256 * a256;
    const float a1024 = a512 * a512;
    const float a2048 = a1024 * a1024;
    const float a2560 = a2048 * a512;  // per-segment multiplier

    // phase-1 reduction weight: a^(4*(63-lane))   (63-lane == lane^63)
    const int li = lane ^ 63;
    float wred = 1.f;
    if (li & 1)  wred *= a4;
    if (li & 2)  wred *= a8;
    if (li & 4)  wred *= a16;
    if (li & 8)  wred *= a32;
    if (li & 16) wred *= a64;
    if (li & 32) wred *= a128;

    // in-round lane position multiplier: a^(4*lane)
    float Aex = 1.f;
    if (lane & 1)  Aex *= a4;
    if (lane & 2)  Aex *= a8;
    if (lane & 4)  Aex *= a16;
    if (lane & 8)  Aex *= a32;
    if (lane & 16) Aex *= a64;
    if (lane & 32) Aex *= a128;

    const float* __restrict__ np_ = noise + (size_t)chain * T_STEPS;
    float* __restrict__       op_ = out   + (size_t)chain * T_STEPS;
    const int segb = wave * SEG;
    const int loff = lane << 2;

    // ---- burst load: entire segment, 10 independent coalesced float4s ----
    // (array fully unrolled -> registers, never scratch)
    float4 c[ROUNDS];
    #pragma unroll
    for (int r = 0; r < ROUNDS; ++r) {
        const int e = segb + (r << 8) + loff;
        if (e + 4 <= T_STEPS) {
            c[r] = *(const float4*)(np_ + e);
        } else {
            c[r] = make_float4(0.f, 0.f, 0.f, 0.f);
        }
    }

    // ---- phase 1: segment offset S_w (per-lane fold, one wave reduce) ----
    float acc = 0.f;
    #pragma unroll
    for (int r = 0; r < ROUNDS; ++r) {
        const int  e  = segb + (r << 8) + loff;
        const bool ar = (e + 4 <= T_STEPS);
        const float b0 = fmaf(ssd, c[r].x, gmdt);
        const float b1 = fmaf(ssd, c[r].y, gmdt);
        const float b2 = fmaf(ssd, c[r].z, gmdt);
        const float b3 = fmaf(ssd, c[r].w, gmdt);
        float p = b0;
        p = fmaf(p, a, b1);
        p = fmaf(p, a, b2);
        p = fmaf(p, a, b3);
        acc = fmaf(acc, a256, ar ? p : 0.f);
    }
    {
        float v = wred * acc;
        v += __shfl_xor(v, 1);
        v += __shfl_xor(v, 2);
        v += __shfl_xor(v, 4);
        v += __shfl_xor(v, 8);
        v += __shfl_xor(v, 16);
        v += __shfl_xor(v, 32);
        if (lane == 0) sS[wave] = v;
    }

    __syncthreads();   // the ONLY barrier; all loads already consumed

    // ---- segment-start state for this wave (uniform walk of 8 values) ----
    float xw;
    {
        float xs = x0;
        float my = x0;
        #pragma unroll
        for (int v = 0; v < NWAVES; ++v) {
            if (wave == v) my = xs;
            xs = fmaf(a2560, xs, sS[v]);
        }
        xw = my;   // state entering round 0 of this wave's segment
        // (wave 7's sS entry is never consumed: its raggedness is harmless)
    }

    // ---- phase 2: replay rounds from registers, scan + store ----
    #pragma unroll
    for (int r = 0; r < ROUNDS; ++r) {
        const int  e  = segb + (r << 8) + loff;
        const bool ar = (e + 4 <= T_STEPS);

        const float b0 = fmaf(ssd, c[r].x, gmdt);
        const float b1 = fmaf(ssd, c[r].y, gmdt);
        const float b2 = fmaf(ssd, c[r].z, gmdt);
        const float b3 = fmaf(ssd, c[r].w, gmdt);
        float p = b0;
        p = fmaf(p, a, b1);
        p = fmaf(p, a, b2);
        p = fmaf(p, a, b3);

        float B = ar ? p : 0.f;

        // uniform-weight inclusive scan (1 shfl + 1 fma per step)
        {
            float t;
            t = __shfl_up(B, 1);  if (lane >= 1)  B = fmaf(a4,   t, B);
            t = __shfl_up(B, 2);  if (lane >= 2)  B = fmaf(a8,   t, B);
            t = __shfl_up(B, 4);  if (lane >= 4)  B = fmaf(a16,  t, B);
            t = __shfl_up(B, 8);  if (lane >= 8)  B = fmaf(a32,  t, B);
            t = __shfl_up(B, 16); if (lane >= 16) B = fmaf(a64,  t, B);
            t = __shfl_up(B, 32); if (lane >= 32) B = fmaf(a128, t, B);
        }

        float Bex = __shfl_up(B, 1);
        if (lane == 0) Bex = 0.f;
        float x = fmaf(Aex, xw, Bex);          // state entering this lane

        const float B63 = __shfl(B, 63);
        xw = fmaf(a256, xw, B63);              // round carry (register chain)

        if (ar) {
            f32x4 o;
            x = fmaf(a, x, b0); o.x = x;
            x = fmaf(a, x, b1); o.y = x;
            x = fmaf(a, x, b2); o.z = x;
            x = fmaf(a, x, b3); o.w = x;
            __builtin_nontemporal_store(o, (f32x4*)(op_ + e));
        }
    }
}

extern "C" void kernel_launch(void* const* d_in, const int* in_sizes, int n_in,
                              void* d_out, int out_size, void* d_ws, size_t ws_size,
                              hipStream_t stream) {
    const float* theta = (const float*)d_in[0];
    const float* noise = (const float*)d_in[1];
    float* out = (float*)d_out;

    const int chains = in_sizes[1] / T_STEPS;   // 2048
    ou_scan_kernel<<<chains, BLOCK, 0, stream>>>(theta, noise, out);
}